// Round 12
// baseline (331.904 us; speedup 1.0000x reference)
//
#include <hip/hip_runtime.h>
#include <hip/hip_bf16.h>
#include <stdint.h>

#define NN 4096
#define H4 4

typedef __hip_bfloat16 bf16;
typedef unsigned short ushort_t;
typedef unsigned long long ull_t;
typedef __attribute__((ext_vector_type(4))) float f32x4;
typedef __attribute__((ext_vector_type(8))) short s16x8;
typedef __attribute__((ext_vector_type(2))) _Float16 h16x2;
typedef __attribute__((ext_vector_type(8))) _Float16 h16x8;

__device__ __forceinline__ ushort_t f2bf(float f) {
  unsigned u = __float_as_uint(f);
  return (ushort_t)((u + 0x7fff + ((u >> 16) & 1)) >> 16);
}
__device__ __forceinline__ float bf2f(ushort_t h) {
  return __uint_as_float((unsigned)h << 16);
}
__device__ __forceinline__ s16x8 as_s16x8(uint4 v) {
  union { uint4 u; s16x8 s; } c; c.u = v; return c.s;
}
__device__ __forceinline__ unsigned pkmul(unsigned a, unsigned b) {
  union { unsigned u; h16x2 v; } A, B, R;
  A.u = a; B.u = b;
  R.v = A.v * B.v;
  return R.u;
}
__device__ __forceinline__ unsigned pkmax(unsigned a, unsigned b) {
  union { unsigned u; h16x2 v; } A, B, R;
  A.u = a; B.u = b;
  R.v = __builtin_elementwise_max(A.v, B.v);
  return R.u;
}
__device__ __forceinline__ ushort_t f2h(float f) {
  union { _Float16 h; ushort_t s; } c;
  c.h = (_Float16)f;
  return c.s;
}

// ---------------- adj -> 64-bit row masks ----------------
__global__ __launch_bounds__(256) void k_mask(const int* __restrict__ adj,
                                              ull_t* __restrict__ mask) {
  int row = blockIdx.x, tid = threadIdx.x;
  int lane = tid & 63, wv = tid >> 6;
  const int* arow = adj + (size_t)row * NN;
  for (int c = 0; c < NN; c += 256) {
    int col = c + wv * 64 + lane;
    ull_t b = __ballot(arow[col] != 0);
    if (lane == 0) mask[row * 64 + (c >> 6) + wv] = b;
  }
}

// ---------------- tiled GEMM (fp32 VALU; only gemm3 x2@W2 uses it) ----------------
__global__ __launch_bounds__(256) void k_gemm(const float* __restrict__ A,
                                              const float* __restrict__ B,
                                              const float* __restrict__ bias,
                                              float* __restrict__ C, int M, int K, int Nc) {
  __shared__ float As[16][68];
  __shared__ float Bs[16][68];
  int tid = threadIdx.x;
  int tx = tid & 15, ty = tid >> 4;
  int mBase = blockIdx.y * 64, nBase = blockIdx.x * 64;
  float acc[4][4] = {};
  for (int k0 = 0; k0 < K; k0 += 16) {
#pragma unroll
    for (int l = 0; l < 4; ++l) {
      int idx = l * 256 + tid;
      int m = idx >> 4, k = idx & 15;
      As[k][m] = A[(size_t)(mBase + m) * K + (k0 + k)];
    }
#pragma unroll
    for (int l = 0; l < 4; ++l) {
      int idx = l * 256 + tid;
      int k = idx >> 6, n = idx & 63;
      int gn = nBase + n;
      Bs[k][n] = (gn < Nc) ? B[(size_t)(k0 + k) * Nc + gn] : 0.f;
    }
    __syncthreads();
#pragma unroll
    for (int k = 0; k < 16; ++k) {
      float4 a = *(const float4*)&As[k][ty * 4];
      float4 b = *(const float4*)&Bs[k][tx * 4];
      float av[4] = {a.x, a.y, a.z, a.w};
      float bv[4] = {b.x, b.y, b.z, b.w};
#pragma unroll
      for (int r = 0; r < 4; ++r)
#pragma unroll
        for (int c = 0; c < 4; ++c) acc[r][c] += av[r] * bv[c];
    }
    __syncthreads();
  }
#pragma unroll
  for (int r = 0; r < 4; ++r) {
    int gm = mBase + ty * 4 + r;
#pragma unroll
    for (int c = 0; c < 4; ++c) {
      int gn = nBase + tx * 4 + c;
      if (gn < Nc) {
        float v = acc[r][c];
        if (bias) v += bias[gn];
        C[(size_t)gm * Nc + gn] = v;
      }
    }
  }
}

// ---------------- merged parameter packing (x, W1, lw1, lw2) ----------------
#define APLANE (4096 * 512)
template <int KK, int NC>
__device__ __forceinline__ void packW_dev(const float* __restrict__ W,
                                          ushort_t* __restrict__ pk, int tau, int lane) {
  constexpr int KS = KK / 32;
  constexpr int T = (NC / 16) * KS;
  constexpr int PL = T * 512;
  if (tau >= T) return;
  int q = lane >> 4, nn = lane & 15;
  int ct = tau / KS, ks = tau % KS;
  ushort_t hi[8], lo[8];
#pragma unroll
  for (int u = 0; u < 8; ++u) {
    float v = W[(size_t)(ks * 32 + q * 8 + u) * NC + ct * 16 + nn];
    hi[u] = f2bf(v);
    lo[u] = f2bf(v - bf2f(hi[u]));
  }
  size_t idx = ((size_t)(ct * KS + ks) * 64 + lane) * 8;
  *(uint4*)&pk[idx] = *(uint4*)hi;
  *(uint4*)&pk[PL + idx] = *(uint4*)lo;
}

__global__ __launch_bounds__(256) void k_packP(const float* __restrict__ x,
                                               const float* __restrict__ W1,
                                               const float* __restrict__ lw1,
                                               const float* __restrict__ lw2,
                                               ushort_t* __restrict__ pkA,
                                               ushort_t* __restrict__ pkW1,
                                               ushort_t* __restrict__ pkLW1,
                                               ushort_t* __restrict__ pkLW2) {
  int b = blockIdx.x, t = threadIdx.x;
  int w = t >> 6, lane = t & 63;
  if (b < 1024) {  // packA: x[4096][512] -> A-tiles hi/lo
    int q = lane >> 4, nn = lane & 15;
    int tau = b * 4 + w;
    int mt = tau >> 4, ks = tau & 15;
    const float* src = &x[(size_t)(mt * 16 + nn) * 512 + ks * 32 + q * 8];
    float4 v0 = *(const float4*)src;
    float4 v1 = *(const float4*)(src + 4);
    float vv[8] = {v0.x, v0.y, v0.z, v0.w, v1.x, v1.y, v1.z, v1.w};
    ushort_t hi[8], lo[8];
#pragma unroll
    for (int u = 0; u < 8; ++u) {
      hi[u] = f2bf(vv[u]);
      lo[u] = f2bf(vv[u] - bf2f(hi[u]));
    }
    size_t idx = ((size_t)(mt * 16 + ks) * 64 + lane) * 8;
    *(uint4*)&pkA[idx] = *(uint4*)hi;
    *(uint4*)&pkA[APLANE + idx] = *(uint4*)lo;
  } else if (b < 1152) {
    packW_dev<512, 512>(W1, pkW1, (b - 1024) * 4 + w, lane);
  } else if (b < 1168) {
    packW_dev<512, 64>(lw1, pkLW1, (b - 1152) * 4 + w, lane);
  } else {
    packW_dev<128, 16>(lw2, pkLW2, (b - 1168) * 4 + w, lane);
  }
}

// ---------------- h1 = x @ W1 via split-bf16 MFMA ----------------
__global__ __launch_bounds__(256, 1) void k_mm1(const uint4* __restrict__ pkA,
                                                const uint4* __restrict__ pkW,
                                                float* __restrict__ h1) {
  constexpr int APL4 = APLANE / 8;
  constexpr int WPL4 = (512 / 16) * (512 / 32) * 64;
  int t = threadIdx.x;
  int w = t >> 6, lane = t & 63;
  int q = lane >> 4, nn = lane & 15;
  int mt0 = blockIdx.x * 4 + (w & 1) * 2;
  int ct0 = blockIdx.y * 8 + (w >> 1) * 4;
  f32x4 acc[2][4];
#pragma unroll
  for (int rt = 0; rt < 2; ++rt)
#pragma unroll
    for (int c = 0; c < 4; ++c)
#pragma unroll
      for (int k = 0; k < 4; ++k) acc[rt][c][k] = 0.f;
#pragma unroll
  for (int ks = 0; ks < 16; ++ks) {
    int ia0 = (mt0 * 16 + ks) * 64 + lane;
    int ia1 = ((mt0 + 1) * 16 + ks) * 64 + lane;
    uint4 ah0 = pkA[ia0], ah1 = pkA[ia1];
    uint4 al0 = pkA[APL4 + ia0], al1 = pkA[APL4 + ia1];
    uint4 bh[4], bl[4];
#pragma unroll
    for (int c = 0; c < 4; ++c) {
      int ib = ((ct0 + c) * 16 + ks) * 64 + lane;
      bh[c] = pkW[ib];
      bl[c] = pkW[WPL4 + ib];
    }
#pragma unroll
    for (int c = 0; c < 4; ++c) {
      acc[0][c] = __builtin_amdgcn_mfma_f32_16x16x32_bf16(as_s16x8(ah0), as_s16x8(bh[c]), acc[0][c], 0, 0, 0);
      acc[0][c] = __builtin_amdgcn_mfma_f32_16x16x32_bf16(as_s16x8(ah0), as_s16x8(bl[c]), acc[0][c], 0, 0, 0);
      acc[0][c] = __builtin_amdgcn_mfma_f32_16x16x32_bf16(as_s16x8(al0), as_s16x8(bh[c]), acc[0][c], 0, 0, 0);
      acc[1][c] = __builtin_amdgcn_mfma_f32_16x16x32_bf16(as_s16x8(ah1), as_s16x8(bh[c]), acc[1][c], 0, 0, 0);
      acc[1][c] = __builtin_amdgcn_mfma_f32_16x16x32_bf16(as_s16x8(ah1), as_s16x8(bl[c]), acc[1][c], 0, 0, 0);
      acc[1][c] = __builtin_amdgcn_mfma_f32_16x16x32_bf16(as_s16x8(al1), as_s16x8(bh[c]), acc[1][c], 0, 0, 0);
    }
  }
  int rowB = blockIdx.x * 64 + (w & 1) * 32;
#pragma unroll
  for (int rt = 0; rt < 2; ++rt)
#pragma unroll
    for (int c = 0; c < 4; ++c)
#pragma unroll
      for (int reg = 0; reg < 4; ++reg) {
        int gi = rowB + rt * 16 + q * 4 + reg;
        h1[(size_t)gi * 512 + (ct0 + c) * 16 + nn] = acc[rt][c][reg];
      }
}

// ---------------- pack h[N][H4*F] f32 into MFMA B-fragment tiles (fp16) --------
template <int F, int TB>
__global__ __launch_bounds__(TB) void k_pack(const float* __restrict__ h,
                                             ushort_t* __restrict__ pk) {
  constexpr int CTW = TB / 64;
  int t = threadIdx.x;
  int lane = t & 63, ctw = t >> 6;
  int q = lane >> 4, nn = lane & 15;
  int ks = blockIdx.x, hd = blockIdx.y;
#pragma unroll
  for (int ct = ctw; ct < F / 16; ct += CTW) {
    ushort_t v[8];
#pragma unroll
    for (int u = 0; u < 8; ++u)
      v[u] = f2h(h[(size_t)(ks * 32 + q * 8 + u) * (H4 * F) + hd * F + ct * 16 + nn]);
    *(uint4*)&pk[((((size_t)hd * (F / 16) + ct) * (NN / 32) + ks) * 64 + lane) * 8] =
        *(uint4*)v;
  }
}

// ---------------- attention scores -> factorized fp16 exp tables ----------------
// E1=exp(es)*2^-4, E2=exp(0.2es)*2^-4, D1=exp(ed)*2^-4, D2=exp(0.2ed)*2^-4 (fp16).
// u* = mask ? max(E1_i*D1_j, E2_i*D2_j) : 0  ==  exp(lrelu(es+ed)) * 2^-8.
// Scale cancels in softmax normalization. All realistic values normal fp16;
// worst-case clamp(±8) product 34.7K < 65504 — no inf/NaN possible.
template <int F>
__global__ __launch_bounds__(256) void k_scores(const float* __restrict__ h,
                                                const float* __restrict__ a_s,
                                                const float* __restrict__ a_d,
                                                ushort_t* __restrict__ E1s,
                                                ushort_t* __restrict__ E2s,
                                                ushort_t* __restrict__ D1s,
                                                ushort_t* __restrict__ D2s) {
  int idx = blockIdx.x * 256 + threadIdx.x;
  if (idx >= NN * H4) return;
  int n = idx >> 2, hd = idx & 3;
  const float* hp = h + (size_t)n * (H4 * F) + hd * F;
  const float* sp = a_s + hd * F;
  const float* dp = a_d + hd * F;
  float ss = 0.f, sd = 0.f;
#pragma unroll 4
  for (int f = 0; f < F; ++f) {
    float v = hp[f];
    ss += v * sp[f];
    sd += v * dp[f];
  }
  ss = fminf(fmaxf(ss, -8.f), 8.f);
  sd = fminf(fmaxf(sd, -8.f), 8.f);
  int o = hd * NN + n;
  E1s[o] = f2h(__expf(ss) * 0.0625f);
  E2s[o] = f2h(__expf(0.2f * ss) * 0.0625f);
  D1s[o] = f2h(__expf(sd) * 0.0625f);
  D2s[o] = f2h(__expf(0.2f * sd) * 0.0625f);
}

// ---------------- MFMA aggregation: packed-fp16 weights + ones-column row-sum ----
// Wave = 32 rows x all F cols of one head over a j-quarter; block = 4 waves.
// Weight pair = v_pk_mul x2 + v_pk_max + integer mask AND; masked u32 pairs ARE the
// fp16 MFMA A-fragment (no convert). Row-sum via extra all-ones B-tile (acc[rt][CT]),
// reduced with the same 2-barrier LDS tree (row stride F+16); epilogue normalizes and
// writes packed MFMA-A bf16 tiles for the next linear layer.
__device__ __forceinline__ void build_af(unsigned E1pk, unsigned E2pk, unsigned byt,
                                         uint4 d1, uint4 d2, unsigned out[4]) {
  unsigned d1v[4] = {d1.x, d1.y, d1.z, d1.w};
  unsigned d2v[4] = {d2.x, d2.y, d2.z, d2.w};
#pragma unroll
  for (int tp = 0; tp < 4; ++tp) {
    unsigned u = pkmax(pkmul(E1pk, d1v[tp]), pkmul(E2pk, d2v[tp]));
    int mlo = (int)(byt << (31 - 2 * tp)) >> 31;
    int mhi = (int)(byt << (30 - 2 * tp)) >> 31;
    out[tp] = u & (((unsigned)mlo & 0xFFFFu) | ((unsigned)mhi << 16));
  }
}
__device__ __forceinline__ h16x8 as_h16x8(const unsigned w[4]) {
  union { unsigned u[4]; h16x8 v; } c;
  c.u[0] = w[0]; c.u[1] = w[1]; c.u[2] = w[2]; c.u[3] = w[3];
  return c.v;
}

template <int F, int OUTM>
__global__ __launch_bounds__(256, 2) void k_agg_mfma(
    const uint4* __restrict__ pk, const ushort_t* __restrict__ E1s,
    const ushort_t* __restrict__ E2s, const ushort_t* __restrict__ D1s,
    const ushort_t* __restrict__ D2s, const ull_t* __restrict__ mask,
    ushort_t* __restrict__ pkOut) {
  constexpr int CT = F / 16;
  constexpr int RW = F + 16;  // reduce row width (CT tiles + rs tile)
  constexpr int KSO = (H4 * F) / 32;
  constexpr int OPL = NN * H4 * F;
  __shared__ float red[2 * 32 * RW];
  int t = threadIdx.x;
  int w = t >> 6, lane = t & 63;
  int q = lane >> 4, nn = lane & 15;
  int hd = blockIdx.y;
  int rowBase = blockIdx.x * 32;
  int jBase = w * (NN / 4);
  int ia0 = rowBase + nn, ia1 = rowBase + 16 + nn;
  unsigned E1p0 = (unsigned)E1s[hd * NN + ia0] * 0x00010001u;
  unsigned E2p0 = (unsigned)E2s[hd * NN + ia0] * 0x00010001u;
  unsigned E1p1 = (unsigned)E1s[hd * NN + ia1] * 0x00010001u;
  unsigned E2p1 = (unsigned)E2s[hd * NN + ia1] * 0x00010001u;
  const ull_t* mk0p = mask + (size_t)ia0 * 64;
  const ull_t* mk1p = mask + (size_t)ia1 * 64;
  const ushort_t* d1h = D1s + hd * NN;
  const ushort_t* d2h = D2s + hd * NN;

  h16x8 ones;
#pragma unroll
  for (int k = 0; k < 8; ++k) ones[k] = (_Float16)1.0f;

  f32x4 acc[2][CT + 1];
#pragma unroll
  for (int rt = 0; rt < 2; ++rt)
#pragma unroll
    for (int cc = 0; cc <= CT; ++cc)
#pragma unroll
      for (int k = 0; k < 4; ++k) acc[rt][cc][k] = 0.f;

#pragma unroll 2
  for (int jc = 0; jc < NN / 4 / 64; ++jc) {
    int j0 = jBase + jc * 64;
    int ks0 = j0 >> 5;
    uint4 bv[2][CT];
#pragma unroll
    for (int s = 0; s < 2; ++s)
#pragma unroll
      for (int cc = 0; cc < CT; ++cc)
        bv[s][cc] = pk[(size_t)((hd * CT + cc) * (NN / 32) + ks0 + s) * 64 + lane];
    ull_t mk0 = mk0p[j0 >> 6], mk1 = mk1p[j0 >> 6];
    uint4 d1a = *(const uint4*)&d1h[j0 + q * 8];
    uint4 d2a = *(const uint4*)&d2h[j0 + q * 8];
    uint4 d1b = *(const uint4*)&d1h[j0 + 32 + q * 8];
    uint4 d2b = *(const uint4*)&d2h[j0 + 32 + q * 8];
    unsigned a00[4], a01[4], a10[4], a11[4];
    build_af(E1p0, E2p0, (unsigned)(mk0 >> (q * 8)) & 0xffu, d1a, d2a, a00);
    build_af(E1p0, E2p0, (unsigned)(mk0 >> (32 + q * 8)) & 0xffu, d1b, d2b, a01);
    build_af(E1p1, E2p1, (unsigned)(mk1 >> (q * 8)) & 0xffu, d1a, d2a, a10);
    build_af(E1p1, E2p1, (unsigned)(mk1 >> (32 + q * 8)) & 0xffu, d1b, d2b, a11);
    h16x8 A00 = as_h16x8(a00), A01 = as_h16x8(a01);
    h16x8 A10 = as_h16x8(a10), A11 = as_h16x8(a11);
#pragma unroll
    for (int cc = 0; cc < CT; ++cc) {
      union { uint4 u; h16x8 v; } b0, b1;
      b0.u = bv[0][cc]; b1.u = bv[1][cc];
      acc[0][cc] = __builtin_amdgcn_mfma_f32_16x16x32_f16(A00, b0.v, acc[0][cc], 0, 0, 0);
      acc[0][cc] = __builtin_amdgcn_mfma_f32_16x16x32_f16(A01, b1.v, acc[0][cc], 0, 0, 0);
      acc[1][cc] = __builtin_amdgcn_mfma_f32_16x16x32_f16(A10, b0.v, acc[1][cc], 0, 0, 0);
      acc[1][cc] = __builtin_amdgcn_mfma_f32_16x16x32_f16(A11, b1.v, acc[1][cc], 0, 0, 0);
    }
    // row-sum tile (B = ones)
    acc[0][CT] = __builtin_amdgcn_mfma_f32_16x16x32_f16(A00, ones, acc[0][CT], 0, 0, 0);
    acc[0][CT] = __builtin_amdgcn_mfma_f32_16x16x32_f16(A01, ones, acc[0][CT], 0, 0, 0);
    acc[1][CT] = __builtin_amdgcn_mfma_f32_16x16x32_f16(A10, ones, acc[1][CT], 0, 0, 0);
    acc[1][CT] = __builtin_amdgcn_mfma_f32_16x16x32_f16(A11, ones, acc[1][CT], 0, 0, 0);
  }

  // 2-barrier cross-wave reduce over CT+1 tiles (incl. rs)
#define IDX(rt, cc, reg) ((rt * 16 + q * 4 + reg) * RW + cc * 16 + nn)
  if (w == 1 || w == 3) {
    int base = (w >> 1) * 32 * RW;
#pragma unroll
    for (int rt = 0; rt < 2; ++rt)
#pragma unroll
      for (int cc = 0; cc <= CT; ++cc)
#pragma unroll
        for (int reg = 0; reg < 4; ++reg) red[base + IDX(rt, cc, reg)] = acc[rt][cc][reg];
  }
  __syncthreads();
  if (w == 0 || w == 2) {
    int base = (w >> 1) * 32 * RW;
#pragma unroll
    for (int rt = 0; rt < 2; ++rt)
#pragma unroll
      for (int cc = 0; cc <= CT; ++cc)
#pragma unroll
        for (int reg = 0; reg < 4; ++reg) acc[rt][cc][reg] += red[base + IDX(rt, cc, reg)];
  }
  if (w == 2) {
#pragma unroll
    for (int rt = 0; rt < 2; ++rt)
#pragma unroll
      for (int cc = 0; cc <= CT; ++cc)
#pragma unroll
        for (int reg = 0; reg < 4; ++reg) red[32 * RW + IDX(rt, cc, reg)] = acc[rt][cc][reg];
  }
  __syncthreads();
  if (w == 0) {
    float rinv[2][4];
#pragma unroll
    for (int rt = 0; rt < 2; ++rt)
#pragma unroll
      for (int reg = 0; reg < 4; ++reg) {
        float s = acc[rt][CT][reg] + red[32 * RW + IDX(rt, CT, reg)];
        rinv[rt][reg] = (s > 0.f) ? 1.f / s : 0.f;
      }
#pragma unroll
    for (int rt = 0; rt < 2; ++rt)
#pragma unroll
      for (int cc = 0; cc < CT; ++cc)
#pragma unroll
        for (int reg = 0; reg < 4; ++reg) {
          float v = (acc[rt][cc][reg] + red[32 * RW + IDX(rt, cc, reg)]) * rinv[rt][reg];
          int gi = rowBase + rt * 16 + q * 4 + reg;
          int c = hd * F + cc * 16 + nn;
          int mt = gi >> 4, rowin = gi & 15;
          int ks = c >> 5, qp = (c >> 3) & 3, u = c & 7;
          size_t idx = (((size_t)mt * KSO + ks) * 64 + qp * 16 + rowin) * 8 + u;
          ushort_t hi = f2bf(v);
          pkOut[idx] = hi;
          if (OUTM == 1) pkOut[OPL + idx] = f2bf(v - bf2f(hi));
        }
  }
#undef IDX
}

// ---------------- y1 = pkX1(bf16) @ lw1(hi/lo) + lb1, MFMA, K-split x2 ----------------
__global__ __launch_bounds__(256) void k_mm2(const uint4* __restrict__ pkX,
                                             const uint4* __restrict__ pkW,
                                             const float* __restrict__ bias,
                                             float* __restrict__ y) {
  constexpr int WPL4 = 4 * 16 * 64;
  __shared__ float red[2 * 16 * 64];
  int t = threadIdx.x;
  int w = t >> 6, lane = t & 63;
  int q = lane >> 4, nn = lane & 15;
  int mt = blockIdx.x * 2 + (w & 1);
  int kh = w >> 1;
  f32x4 acc[4];
#pragma unroll
  for (int c = 0; c < 4; ++c)
#pragma unroll
    for (int k = 0; k < 4; ++k) acc[c][k] = 0.f;
#pragma unroll
  for (int k8 = 0; k8 < 8; ++k8) {
    int ks = kh * 8 + k8;
    uint4 a = pkX[(mt * 16 + ks) * 64 + lane];
#pragma unroll
    for (int c = 0; c < 4; ++c) {
      uint4 bh = pkW[(c * 16 + ks) * 64 + lane];
      uint4 bl = pkW[WPL4 + (c * 16 + ks) * 64 + lane];
      acc[c] = __builtin_amdgcn_mfma_f32_16x16x32_bf16(as_s16x8(a), as_s16x8(bh), acc[c], 0, 0, 0);
      acc[c] = __builtin_amdgcn_mfma_f32_16x16x32_bf16(as_s16x8(a), as_s16x8(bl), acc[c], 0, 0, 0);
    }
  }
  int base = (w & 1) * 1024;
  if (kh == 1) {
#pragma unroll
    for (int c = 0; c < 4; ++c)
#pragma unroll
      for (int reg = 0; reg < 4; ++reg)
        red[base + (q * 4 + reg) * 64 + c * 16 + nn] = acc[c][reg];
  }
  __syncthreads();
  if (kh == 0) {
#pragma unroll
    for (int c = 0; c < 4; ++c)
#pragma unroll
      for (int reg = 0; reg < 4; ++reg) {
        float v = acc[c][reg] + red[base + (q * 4 + reg) * 64 + c * 16 + nn] + bias[c * 16 + nn];
        y[(size_t)(mt * 16 + q * 4 + reg) * 64 + c * 16 + nn] = v;
      }
  }
}

// ---------------- y2 = pkX3(hi/lo) @ lw2(hi/lo) + lb2, MFMA ----------------
__global__ __launch_bounds__(256) void k_mm4(const uint4* __restrict__ pkX,
                                             const uint4* __restrict__ pkW,
                                             const float* __restrict__ bias,
                                             float* __restrict__ y) {
  constexpr int XPL4 = 256 * 4 * 64;
  constexpr int WPL4 = 1 * 4 * 64;
  int t = threadIdx.x;
  int w = t >> 6, lane = t & 63;
  int q = lane >> 4, nn = lane & 15;
  int mt = blockIdx.x * 4 + w;
  f32x4 acc;
#pragma unroll
  for (int k = 0; k < 4; ++k) acc[k] = 0.f;
#pragma unroll
  for (int ks = 0; ks < 4; ++ks) {
    uint4 ah = pkX[(mt * 4 + ks) * 64 + lane];
    uint4 al = pkX[XPL4 + (mt * 4 + ks) * 64 + lane];
    uint4 bh = pkW[ks * 64 + lane];
    uint4 bl = pkW[WPL4 + ks * 64 + lane];
    acc = __builtin_amdgcn_mfma_f32_16x16x32_bf16(as_s16x8(ah), as_s16x8(bh), acc, 0, 0, 0);
    acc = __builtin_amdgcn_mfma_f32_16x16x32_bf16(as_s16x8(ah), as_s16x8(bl), acc, 0, 0, 0);
    acc = __builtin_amdgcn_mfma_f32_16x16x32_bf16(as_s16x8(al), as_s16x8(bh), acc, 0, 0, 0);
  }
  float b = bias[nn];
#pragma unroll
  for (int reg = 0; reg < 4; ++reg)
    y[(size_t)(mt * 16 + q * 4 + reg) * 16 + nn] = acc[reg] + b;
}

// ---------------- fused per-column BN stats + BN + ELU ----------------
__global__ __launch_bounds__(256) void k_bn_col(const float* __restrict__ y,
                                                const float* __restrict__ gamma,
                                                const float* __restrict__ beta,
                                                float* __restrict__ o, int C) {
  int c = blockIdx.x, tid = threadIdx.x;
  float s = 0.f, s2 = 0.f;
  for (int r = tid; r < NN; r += 256) {
    float v = y[(size_t)r * C + c];
    s += v;
    s2 += v * v;
  }
  __shared__ float sh[256], sh2[256];
  __shared__ float smu, srs;
  sh[tid] = s; sh2[tid] = s2;
  __syncthreads();
  for (int off = 128; off; off >>= 1) {
    if (tid < off) { sh[tid] += sh[tid + off]; sh2[tid] += sh2[tid + off]; }
    __syncthreads();
  }
  if (tid == 0) {
    float mu = sh[0] * (1.f / NN);
    float var = sh2[0] * (1.f / NN) - mu * mu;
    smu = mu;
    srs = rsqrtf(fmaxf(var, 0.f) + 1e-5f);
  }
  __syncthreads();
  float mu = smu, rstd = srs, g = gamma[c], b = beta[c];
  for (int r = tid; r < NN; r += 256) {
    float v = (y[(size_t)r * C + c] - mu) * rstd * g + b;
    v = v > 0.f ? v : (__expf(v) - 1.f);
    o[(size_t)r * C + c] = v;
  }
}

extern "C" void kernel_launch(void* const* d_in, const int* in_sizes, int n_in,
                              void* d_out, int out_size, void* d_ws, size_t ws_size,
                              hipStream_t stream) {
  (void)in_sizes; (void)n_in; (void)out_size; (void)ws_size;
  const float* x   = (const float*)d_in[0];
  const int*   adj = (const int*)d_in[1];
  const float* W1  = (const float*)d_in[2];
  const float* a1s = (const float*)d_in[3];
  const float* a1d = (const float*)d_in[4];
  const float* lw1 = (const float*)d_in[5];
  const float* lb1 = (const float*)d_in[6];
  const float* g1  = (const float*)d_in[7];
  const float* be1 = (const float*)d_in[8];
  const float* W2  = (const float*)d_in[9];
  const float* a2s = (const float*)d_in[10];
  const float* a2d = (const float*)d_in[11];
  const float* lw2 = (const float*)d_in[12];
  const float* lb2 = (const float*)d_in[13];
  const float* g2  = (const float*)d_in[14];
  const float* be2 = (const float*)d_in[15];
  float* out = (float*)d_out;

  // ---- workspace: LINEAR layout, no overlays (~38 MB of >=268 MB) ----
  char* w = (char*)d_ws;
  const size_t MB = 1u << 20;
  ull_t*    mask  = (ull_t*)(w + 0);              // 2 MB
  ushort_t* pkA   = (ushort_t*)(w + 2 * MB);      // 8 MB
  ushort_t* pkW1  = (ushort_t*)(w + 10 * MB);     // 1 MB
  float*    h1    = (float*)(w + 11 * MB);        // 8 MB
  ushort_t* pk1   = (ushort_t*)(w + 19 * MB);     // 4 MB (fp16 B-tiles)
  ushort_t* E1a   = (ushort_t*)(w + 23 * MB);     // 4 x 32 KB fp16 tables
  ushort_t* E2a   = E1a + 16384;
  ushort_t* D1a   = E2a + 16384;
  ushort_t* D2a   = D1a + 16384;
  ushort_t* pkX1  = (ushort_t*)(w + 24 * MB);     // 4 MB
  ushort_t* pkLW1 = (ushort_t*)(w + 28 * MB);     // 128 KB
  float*    y1    = (float*)(w + 29 * MB);        // 1 MB
  float*    x2    = (float*)(w + 30 * MB);        // 1 MB
  float*    h2    = (float*)(w + 31 * MB);        // 2 MB
  ushort_t* pk2   = (ushort_t*)(w + 33 * MB);     // 1 MB (fp16 B-tiles)
  ushort_t* E1b   = (ushort_t*)(w + 34 * MB);     // 4 x 32 KB
  ushort_t* E2b   = E1b + 16384;
  ushort_t* D1b   = E2b + 16384;
  ushort_t* D2b   = D1b + 16384;
  ushort_t* pkX3  = (ushort_t*)(w + 35 * MB);     // 2 MB
  ushort_t* pkLW2 = (ushort_t*)(w + 37 * MB);     // 8 KB
  float*    y2    = (float*)(w + 37 * MB + 131072);  // 256 KB

  k_mask<<<NN, 256, 0, stream>>>(adj, mask);
  k_packP<<<1169, 256, 0, stream>>>(x, W1, lw1, lw2, pkA, pkW1, pkLW1, pkLW2);

  // ---- layer 1 GAT ----
  k_mm1<<<dim3(64, 4), 256, 0, stream>>>((const uint4*)pkA, (const uint4*)pkW1, h1);
  k_pack<128, 256><<<dim3(NN / 32, H4), 256, 0, stream>>>(h1, pk1);
  k_scores<128><<<(NN * H4) / 256, 256, 0, stream>>>(h1, a1s, a1d, E1a, E2a, D1a, D2a);
  k_agg_mfma<128, 0><<<dim3(NN / 32, H4), 256, 0, stream>>>((const uint4*)pk1, E1a, E2a,
                                                            D1a, D2a, mask, pkX1);

  // ---- linear + BN + ELU ----
  k_mm2<<<128, 256, 0, stream>>>((const uint4*)pkX1, (const uint4*)pkLW1, lb1, y1);
  k_bn_col<<<64, 256, 0, stream>>>(y1, g1, be1, x2, 64);

  // ---- layer 2 GAT ----
  k_gemm<<<dim3(2, 64), 256, 0, stream>>>(x2, W2, nullptr, h2, NN, 64, 128);
  k_pack<32, 128><<<dim3(NN / 32, H4), 128, 0, stream>>>(h2, pk2);
  k_scores<32><<<(NN * H4) / 256, 256, 0, stream>>>(h2, a2s, a2d, E1b, E2b, D1b, D2b);
  k_agg_mfma<32, 1><<<dim3(NN / 32, H4), 256, 0, stream>>>((const uint4*)pk2, E1b, E2b,
                                                           D1b, D2b, mask, pkX3);

  // ---- final linear + BN + ELU ----
  k_mm4<<<64, 256, 0, stream>>>((const uint4*)pkX3, (const uint4*)pkLW2, lb2, y2);
  k_bn_col<<<16, 256, 0, stream>>>(y2, g2, be2, out, 16);
}